// Round 29
// baseline (295.219 us; speedup 1.0000x reference)
//
#include <hip/hip_runtime.h>

typedef __attribute__((ext_vector_type(4))) float f32x4;
typedef __attribute__((ext_vector_type(8))) short bf16x8;

__device__ __forceinline__ unsigned short f2bf(float f){
  unsigned int x = __float_as_uint(f);
  return (unsigned short)((x + 0x7fffu + ((x >> 16) & 1u)) >> 16); // RNE
}

// packed f32x2 -> bf16x2 (gfx950 native, RNE)
__device__ __forceinline__ unsigned int cvt2(float lo, float hi){
  unsigned int r;
  asm("v_cvt_pk_bf16_f32 %0, %1, %2" : "=v"(r) : "v"(lo), "v"(hi));
  return r;
}

// ---------------- SE3 via explicit rotation matrices (fp32, exact) ----------------
struct Q  { float w,x,y,z; };
struct V3 { float x,y,z; };
struct M3 { float m[9]; };

__device__ __forceinline__ Q qmul(Q a, Q b){
  return { a.w*b.w - a.x*b.x - a.y*b.y - a.z*b.z,
           a.w*b.x + a.x*b.w + a.y*b.z - a.z*b.y,
           a.w*b.y - a.x*b.z + a.y*b.w + a.z*b.x,
           a.w*b.z + a.x*b.y - a.y*b.x + a.z*b.w };
}
__device__ __forceinline__ Q qconj(Q q){ return { q.w, -q.x, -q.y, -q.z }; }
__device__ __forceinline__ M3 q2R(Q q){
  const float w=q.w, x=q.x, y=q.y, z=q.z;
  M3 R;
  R.m[0]=1.f-2.f*(y*y+z*z); R.m[1]=2.f*(x*y-w*z);     R.m[2]=2.f*(x*z+w*y);
  R.m[3]=2.f*(x*y+w*z);     R.m[4]=1.f-2.f*(x*x+z*z); R.m[5]=2.f*(y*z-w*x);
  R.m[6]=2.f*(x*z-w*y);     R.m[7]=2.f*(y*z+w*x);     R.m[8]=1.f-2.f*(x*x+y*y);
  return R;
}
__device__ __forceinline__ V3 mv (M3 R, V3 v){
  return { R.m[0]*v.x + R.m[1]*v.y + R.m[2]*v.z,
           R.m[3]*v.x + R.m[4]*v.y + R.m[5]*v.z,
           R.m[6]*v.x + R.m[7]*v.y + R.m[8]*v.z };
}
__device__ __forceinline__ V3 mtv(M3 R, V3 v){
  return { R.m[0]*v.x + R.m[3]*v.y + R.m[6]*v.z,
           R.m[1]*v.x + R.m[4]*v.y + R.m[7]*v.z,
           R.m[2]*v.x + R.m[5]*v.y + R.m[8]*v.z };
}

// ---------------- prep: bf16 W panels, B-fragment-ready [col][k] ----------------
__global__ void prep_kernel(const float* __restrict__ W1, const float* __restrict__ W2,
                            unsigned short* __restrict__ W1p, unsigned short* __restrict__ W2p){
  const int N1 = 128*544;
  int gid = blockIdx.x*256 + threadIdx.x;
  if (gid < N1){
    int c = gid / 544, k = gid % 544;
    W1p[gid] = (k < 519) ? f2bf(W1[(size_t)k*128 + c]) : (unsigned short)0;
  } else if (gid < N1 + 128*128){
    int g = gid - N1;
    int c = g >> 7, k = g & 127;
    W2p[g] = f2bf(W2[(size_t)k*128 + c]);
  }
}

// ---------------- main kernel: 64 edges/block, 8 waves (16 cols x 64 edges) ----------
// R28 data paths; prologue phases fused (slab0-stage hoisted; SE3 || u-gather ||
// consume0 barrier-free on disjoint LDS regions); setprio around MFMA clusters.
template<bool WSP>
__global__ __launch_bounds__(512) void edge_k(
    const float* __restrict__ xfi, const float* __restrict__ xfj, const float* __restrict__ ef,
    const float* __restrict__ Ti,  const float* __restrict__ Tj,  const float* __restrict__ Th,
    const int*   __restrict__ batch, const float* __restrict__ u,
    const float* __restrict__ W1,  const float* __restrict__ b1,
    const float* __restrict__ W2,  const float* __restrict__ b2,
    const unsigned short* __restrict__ W1p, const unsigned short* __restrict__ W2p,
    float* __restrict__ outE, float* __restrict__ outT, int E)
{
  __shared__ __align__(16) unsigned short tailb[64][168]; // k=384..543: Terr|u|pad
  __shared__ __align__(16) unsigned short fbuf[64][136];  // current 128-k feature slab
  __shared__ __align__(16) unsigned short hbf[64][136];   // h bf16 (dedicated — R19 law)
  __shared__ float tib[448], tjb[448], thb[448];          // staged SE3 inputs (coalesced)

  const int tid = threadIdx.x;              // 0..511 (8 waves)
  const long base = (long)blockIdx.x * 64;

  // ---- Phase 0a: stage slab 0 (xfi) into fbuf ----
  #pragma unroll
  for (int i = 0; i < 4; ++i){
    const int idx = i*512 + tid;
    const int e = idx >> 5, c4 = (idx & 31) << 2;
    long rr = base + e; if (rr >= E) rr = E-1;
    const float4 v = *reinterpret_cast<const float4*>(xfi + (size_t)rr*128 + c4);
    unsigned int* dst = reinterpret_cast<unsigned int*>(&fbuf[e][c4]);
    dst[0] = cvt2(v.x, v.y);
    dst[1] = cvt2(v.z, v.w);
  }

  // ---- Phase 0b: coalesced SE3-input staging + Tij_hat passthrough ----
  {
    const long flatBase = base * 7;
    const long flatMax  = (long)E * 7;
    if (tid < 448){
      long fi = flatBase + tid; if (fi >= flatMax) fi = flatMax - 1;
      const float vi = Ti[fi], vj = Tj[fi], vh = Th[fi];
      tib[tid] = vi; tjb[tid] = vj; thb[tid] = vh;
      if (flatBase + tid < flatMax) outT[flatBase + tid] = vh;
    }
  }
  __syncthreads();   // B1: tib/tjb/thb + fbuf ready

  // ---- Phase 1 (barrier-free concurrent): SE3 (tid<64) || u-gather || pad ----
  if (tid < 64){
    const float* pi = &tib[tid*7];
    const float* pj = &tjb[tid*7];
    const float* ph = &thb[tid*7];
    Q  qi{pi[0],pi[1],pi[2],pi[3]};  V3 tti{pi[4],pi[5],pi[6]};
    Q  qj{pj[0],pj[1],pj[2],pj[3]};  V3 ttj{pj[4],pj[5],pj[6]};
    Q  qh{ph[0],ph[1],ph[2],ph[3]};  V3 tth{ph[4],ph[5],ph[6]};
    M3 Ri = q2R(qi), Rj = q2R(qj), Rh = q2R(qh);
    V3 a  = mtv(Rj, ttj);
    V3 bv = mv(Ri, a);
    V3 c  { tti.x - bv.x, tti.y - bv.y, tti.z - bv.z };
    V3 d  = mv(Rh, c);
    Q  qe = qmul(qmul(qh, qi), qconj(qj));
    tailb[tid][0] = f2bf(qe.w);
    tailb[tid][1] = f2bf(qe.x);
    tailb[tid][2] = f2bf(qe.y);
    tailb[tid][3] = f2bf(qe.z);
    tailb[tid][4] = f2bf(tth.x + d.x);
    tailb[tid][5] = f2bf(tth.y + d.y);
    tailb[tid][6] = f2bf(tth.z + d.z);
  }
  // u-gather: batch read directly (L1-broadcast), disjoint tailb cols 7..134
  for (int idx = tid; idx < 64*128; idx += 512){
    const int e = idx >> 7, c = idx & 127;
    long rc = base + e; if (rc >= E) rc = E-1;
    tailb[e][7 + c] = f2bf(u[(size_t)batch[rc]*128 + c]);
  }
  for (int idx = tid; idx < 64*33; idx += 512){
    const int e = idx / 33, c = idx % 33;
    tailb[e][135 + c] = 0;
  }

  const int lane = tid & 63, wv = tid >> 6;   // 8 waves; wave owns cols [16wv, 16wv+16)
  const int l15 = lane & 15, l4 = lane >> 4;
  const int col = wv*16 + l15;

  // ---- GEMM1 accumulators ----
  f32x4 acc1[4];
  {
    const float bv = b1[col];
    #pragma unroll
    for (int a = 0; a < 4; ++a){
      #pragma unroll
      for (int r = 0; r < 4; ++r) acc1[a][r] = bv;
    }
  }

  // ---- consume slab 0 (concurrent with phase 1 on other waves) ----
  __builtin_amdgcn_s_setprio(1);
  #pragma unroll
  for (int kc = 0; kc < 4; ++kc){
    const int kl = kc*32 + l4*8;
    bf16x8 afr[4];
    #pragma unroll
    for (int a = 0; a < 4; ++a)
      afr[a] = *reinterpret_cast<const bf16x8*>(&fbuf[a*16 + l15][kl]);
    bf16x8 Bv;
    if (WSP){
      Bv = *reinterpret_cast<const bf16x8*>(W1p + (size_t)col*544 + kl);
    } else {
      float w[8];
      #pragma unroll
      for (int j = 0; j < 8; ++j)
        w[j] = W1[(size_t)(kl + j)*128 + col];
      union { bf16x8 v; unsigned int ui[4]; } B;
      B.ui[0] = cvt2(w[0], w[1]);
      B.ui[1] = cvt2(w[2], w[3]);
      B.ui[2] = cvt2(w[4], w[5]);
      B.ui[3] = cvt2(w[6], w[7]);
      Bv = B.v;
    }
    #pragma unroll
    for (int a = 0; a < 4; ++a)
      acc1[a] = __builtin_amdgcn_mfma_f32_16x16x32_bf16(afr[a], Bv, acc1[a], 0, 0, 0);
  }
  __builtin_amdgcn_s_setprio(0);

  // ---- slabs 1,2: stage + consume ----
  const float* fps[3] = { xfi, xfj, ef };
  for (int fb = 1; fb < 3; ++fb){
    const float* F = fps[fb];
    __syncthreads();                         // previous slab consumed
    #pragma unroll
    for (int i = 0; i < 4; ++i){
      const int idx = i*512 + tid;
      const int e = idx >> 5, c4 = (idx & 31) << 2;
      long rr = base + e; if (rr >= E) rr = E-1;
      const float4 v = *reinterpret_cast<const float4*>(F + (size_t)rr*128 + c4);
      unsigned int* dst = reinterpret_cast<unsigned int*>(&fbuf[e][c4]);
      dst[0] = cvt2(v.x, v.y);
      dst[1] = cvt2(v.z, v.w);
    }
    __syncthreads();
    __builtin_amdgcn_s_setprio(1);
    #pragma unroll
    for (int kc = 0; kc < 4; ++kc){
      const int kl = kc*32 + l4*8;
      bf16x8 afr[4];
      #pragma unroll
      for (int a = 0; a < 4; ++a)
        afr[a] = *reinterpret_cast<const bf16x8*>(&fbuf[a*16 + l15][kl]);
      bf16x8 Bv;
      if (WSP){
        Bv = *reinterpret_cast<const bf16x8*>(W1p + (size_t)col*544 + fb*128 + kl);
      } else {
        float w[8];
        #pragma unroll
        for (int j = 0; j < 8; ++j)
          w[j] = W1[(size_t)(fb*128 + kl + j)*128 + col];
        union { bf16x8 v; unsigned int ui[4]; } B;
        B.ui[0] = cvt2(w[0], w[1]);
        B.ui[1] = cvt2(w[2], w[3]);
        B.ui[2] = cvt2(w[4], w[5]);
        B.ui[3] = cvt2(w[6], w[7]);
        Bv = B.v;
      }
      #pragma unroll
      for (int a = 0; a < 4; ++a)
        acc1[a] = __builtin_amdgcn_mfma_f32_16x16x32_bf16(afr[a], Bv, acc1[a], 0, 0, 0);
    }
    __builtin_amdgcn_s_setprio(0);
  }

  // ---- tail k-chunks (k = 384..543) from tailb (writes covered by slab-1 barrier) ----
  __builtin_amdgcn_s_setprio(1);
  #pragma unroll
  for (int tc = 0; tc < 5; ++tc){
    const int kt = tc*32 + l4*8;
    bf16x8 afr[4];
    #pragma unroll
    for (int a = 0; a < 4; ++a)
      afr[a] = *reinterpret_cast<const bf16x8*>(&tailb[a*16 + l15][kt]);
    bf16x8 Bv;
    if (WSP){
      Bv = *reinterpret_cast<const bf16x8*>(W1p + (size_t)col*544 + 384 + kt);
    } else {
      float w[8];
      #pragma unroll
      for (int j = 0; j < 8; ++j){
        const int kk = 384 + kt + j;
        w[j] = (kk < 519) ? W1[(size_t)kk*128 + col] : 0.f;
      }
      union { bf16x8 v; unsigned int ui[4]; } B;
      B.ui[0] = cvt2(w[0], w[1]);
      B.ui[1] = cvt2(w[2], w[3]);
      B.ui[2] = cvt2(w[4], w[5]);
      B.ui[3] = cvt2(w[6], w[7]);
      Bv = B.v;
    }
    #pragma unroll
    for (int a = 0; a < 4; ++a)
      acc1[a] = __builtin_amdgcn_mfma_f32_16x16x32_bf16(afr[a], Bv, acc1[a], 0, 0, 0);
  }
  __builtin_amdgcn_s_setprio(0);

  // ---- h = relu -> bf16 into dedicated hbf ----
  #pragma unroll
  for (int a = 0; a < 4; ++a){
    #pragma unroll
    for (int r = 0; r < 4; ++r)
      hbf[a*16 + l4*4 + r][col] = f2bf(fmaxf(acc1[a][r], 0.f));
  }
  __syncthreads();

  // ---- GEMM2: out = ef (fp32 global, late init) + b2 + h @ W2 ----
  f32x4 acc2[4];
  {
    const float bv2 = b2[col];
    #pragma unroll
    for (int a = 0; a < 4; ++a){
      #pragma unroll
      for (int r = 0; r < 4; ++r){
        long orow = base + a*16 + l4*4 + r;
        if (orow >= E) orow = E-1;
        acc2[a][r] = ef[(size_t)orow*128 + col] + bv2;
      }
    }
  }
  __builtin_amdgcn_s_setprio(1);
  #pragma unroll
  for (int ks = 0; ks < 4; ++ks){
    const int k0 = ks*32 + l4*8;
    bf16x8 afr[4];
    #pragma unroll
    for (int a = 0; a < 4; ++a)
      afr[a] = *reinterpret_cast<const bf16x8*>(&hbf[a*16 + l15][k0]);
    bf16x8 Bv;
    if (WSP){
      Bv = *reinterpret_cast<const bf16x8*>(W2p + (size_t)col*128 + k0);
    } else {
      float w[8];
      #pragma unroll
      for (int j = 0; j < 8; ++j)
        w[j] = W2[(size_t)(k0 + j)*128 + col];
      union { bf16x8 v; unsigned int ui[4]; } B;
      B.ui[0] = cvt2(w[0], w[1]);
      B.ui[1] = cvt2(w[2], w[3]);
      B.ui[2] = cvt2(w[4], w[5]);
      B.ui[3] = cvt2(w[6], w[7]);
      Bv = B.v;
    }
    #pragma unroll
    for (int a = 0; a < 4; ++a)
      acc2[a] = __builtin_amdgcn_mfma_f32_16x16x32_bf16(afr[a], Bv, acc2[a], 0, 0, 0);
  }
  __builtin_amdgcn_s_setprio(0);

  // ---- store edge_feat_out ----
  #pragma unroll
  for (int a = 0; a < 4; ++a){
    #pragma unroll
    for (int r = 0; r < 4; ++r){
      const long orow = base + a*16 + l4*4 + r;
      if (orow < E) outE[(size_t)orow*128 + col] = acc2[a][r];
    }
  }
}

extern "C" void kernel_launch(void* const* d_in, const int* in_sizes, int n_in,
                              void* d_out, int out_size, void* d_ws, size_t ws_size,
                              hipStream_t stream){
  const float* xfi  = (const float*)d_in[0];
  const float* xfj  = (const float*)d_in[1];
  const float* ef   = (const float*)d_in[2];
  const float* Ti   = (const float*)d_in[3];
  const float* Tj   = (const float*)d_in[4];
  const float* Th   = (const float*)d_in[5];
  const float* u    = (const float*)d_in[6];
  const int*   bat  = (const int*)d_in[7];
  const float* W1   = (const float*)d_in[8];
  const float* b1   = (const float*)d_in[9];
  const float* W2   = (const float*)d_in[10];
  const float* b2   = (const float*)d_in[11];
  const int E = in_sizes[0] / 128;

  float* outE = (float*)d_out;
  float* outT = outE + (size_t)E * 128;

  const int grid = (E + 63) / 64;
  const size_t need = (size_t)(128*544 + 128*128) * sizeof(unsigned short); // 172032 B
  if (d_ws != nullptr && ws_size >= need){
    unsigned short* W1p = (unsigned short*)d_ws;
    unsigned short* W2p = W1p + (size_t)128*544;
    prep_kernel<<<(128*544 + 128*128 + 255)/256, 256, 0, stream>>>(W1, W2, W1p, W2p);
    edge_k<true><<<grid, 512, 0, stream>>>(xfi, xfj, ef, Ti, Tj, Th, bat, u,
                                           W1, b1, W2, b2, W1p, W2p, outE, outT, E);
  } else {
    edge_k<false><<<grid, 512, 0, stream>>>(xfi, xfj, ef, Ti, Tj, Th, bat, u,
                                            W1, b1, W2, b2, nullptr, nullptr, outE, outT, E);
  }
}

// Round 30
// 282.917 us; speedup vs baseline: 1.0435x; 1.0435x over previous
//
#include <hip/hip_runtime.h>

typedef __attribute__((ext_vector_type(4))) float f32x4;
typedef __attribute__((ext_vector_type(8))) short bf16x8;

__device__ __forceinline__ unsigned short f2bf(float f){
  unsigned int x = __float_as_uint(f);
  return (unsigned short)((x + 0x7fffu + ((x >> 16) & 1u)) >> 16); // RNE
}

// packed f32x2 -> bf16x2 (gfx950 native, RNE)
__device__ __forceinline__ unsigned int cvt2(float lo, float hi){
  unsigned int r;
  asm("v_cvt_pk_bf16_f32 %0, %1, %2" : "=v"(r) : "v"(lo), "v"(hi));
  return r;
}

// ---------------- SE3 via explicit rotation matrices (fp32, exact) ----------------
struct Q  { float w,x,y,z; };
struct V3 { float x,y,z; };
struct M3 { float m[9]; };

__device__ __forceinline__ Q qmul(Q a, Q b){
  return { a.w*b.w - a.x*b.x - a.y*b.y - a.z*b.z,
           a.w*b.x + a.x*b.w + a.y*b.z - a.z*b.y,
           a.w*b.y - a.x*b.z + a.y*b.w + a.z*b.x,
           a.w*b.z + a.x*b.y - a.y*b.x + a.z*b.w };
}
__device__ __forceinline__ Q qconj(Q q){ return { q.w, -q.x, -q.y, -q.z }; }
__device__ __forceinline__ M3 q2R(Q q){
  const float w=q.w, x=q.x, y=q.y, z=q.z;
  M3 R;
  R.m[0]=1.f-2.f*(y*y+z*z); R.m[1]=2.f*(x*y-w*z);     R.m[2]=2.f*(x*z+w*y);
  R.m[3]=2.f*(x*y+w*z);     R.m[4]=1.f-2.f*(x*x+z*z); R.m[5]=2.f*(y*z-w*x);
  R.m[6]=2.f*(x*z-w*y);     R.m[7]=2.f*(y*z+w*x);     R.m[8]=1.f-2.f*(x*x+y*y);
  return R;
}
__device__ __forceinline__ V3 mv (M3 R, V3 v){
  return { R.m[0]*v.x + R.m[1]*v.y + R.m[2]*v.z,
           R.m[3]*v.x + R.m[4]*v.y + R.m[5]*v.z,
           R.m[6]*v.x + R.m[7]*v.y + R.m[8]*v.z };
}
__device__ __forceinline__ V3 mtv(M3 R, V3 v){
  return { R.m[0]*v.x + R.m[3]*v.y + R.m[6]*v.z,
           R.m[1]*v.x + R.m[4]*v.y + R.m[7]*v.z,
           R.m[2]*v.x + R.m[5]*v.y + R.m[8]*v.z };
}

// ---------------- prep: bf16 W panels, B-fragment-ready [col][k] ----------------
__global__ void prep_kernel(const float* __restrict__ W1, const float* __restrict__ W2,
                            unsigned short* __restrict__ W1p, unsigned short* __restrict__ W2p){
  const int N1 = 128*544;
  int gid = blockIdx.x*256 + threadIdx.x;
  if (gid < N1){
    int c = gid / 544, k = gid % 544;
    W1p[gid] = (k < 519) ? f2bf(W1[(size_t)k*128 + c]) : (unsigned short)0;
  } else if (gid < N1 + 128*128){
    int g = gid - N1;
    int c = g >> 7, k = g & 127;
    W2p[g] = f2bf(W2[(size_t)k*128 + c]);
  }
}

// ---------------- main kernel: 64 edges/block, 8 waves (16 cols x 64 edges) ----------
// Session optimum (R28): A via LDS bf16 slabs, B via bf16 d_ws panels (1 vector load),
// packed v_cvt_pk_bf16_f32 staging, coalesced SE3-input staging, dedicated hbf,
// fp32 late ef residual. 283 us @ MfmaUtil 11.4%, VALUBusy 22%, Occ 44%.
template<bool WSP>
__global__ __launch_bounds__(512) void edge_k(
    const float* __restrict__ xfi, const float* __restrict__ xfj, const float* __restrict__ ef,
    const float* __restrict__ Ti,  const float* __restrict__ Tj,  const float* __restrict__ Th,
    const int*   __restrict__ batch, const float* __restrict__ u,
    const float* __restrict__ W1,  const float* __restrict__ b1,
    const float* __restrict__ W2,  const float* __restrict__ b2,
    const unsigned short* __restrict__ W1p, const unsigned short* __restrict__ W2p,
    float* __restrict__ outE, float* __restrict__ outT, int E)
{
  __shared__ __align__(16) unsigned short tailb[64][168]; // k=384..543: Terr|u|pad
  __shared__ __align__(16) unsigned short fbuf[64][136];  // current 128-k feature slab
  __shared__ __align__(16) unsigned short hbf[64][136];   // h bf16 (dedicated — R19 law)
  __shared__ float tib[448], tjb[448], thb[448];          // staged SE3 inputs (coalesced)
  __shared__ int ibat_s[64];

  const int tid = threadIdx.x;              // 0..511 (8 waves)
  const long base = (long)blockIdx.x * 64;

  // ---- Phase 0: coalesced SE3-input staging + Tij_hat passthrough ----
  {
    const long flatBase = base * 7;
    const long flatMax  = (long)E * 7;
    if (tid < 448){
      long fi = flatBase + tid; if (fi >= flatMax) fi = flatMax - 1;
      const float vi = Ti[fi], vj = Tj[fi], vh = Th[fi];
      tib[tid] = vi; tjb[tid] = vj; thb[tid] = vh;
      if (flatBase + tid < flatMax) outT[flatBase + tid] = vh;
    }
  }
  __syncthreads();

  // ---- Phase 1: SE3 error (threads 0..63, inputs from LDS) ----
  if (tid < 64){
    const long row = base + tid;
    const long rc  = row < E ? row : (long)(E-1);
    const float* pi = &tib[tid*7];
    const float* pj = &tjb[tid*7];
    const float* ph = &thb[tid*7];
    Q  qi{pi[0],pi[1],pi[2],pi[3]};  V3 tti{pi[4],pi[5],pi[6]};
    Q  qj{pj[0],pj[1],pj[2],pj[3]};  V3 ttj{pj[4],pj[5],pj[6]};
    Q  qh{ph[0],ph[1],ph[2],ph[3]};  V3 tth{ph[4],ph[5],ph[6]};
    M3 Ri = q2R(qi), Rj = q2R(qj), Rh = q2R(qh);
    V3 a  = mtv(Rj, ttj);
    V3 bv = mv(Ri, a);
    V3 c  { tti.x - bv.x, tti.y - bv.y, tti.z - bv.z };
    V3 d  = mv(Rh, c);
    Q  qe = qmul(qmul(qh, qi), qconj(qj));
    tailb[tid][0] = f2bf(qe.w);
    tailb[tid][1] = f2bf(qe.x);
    tailb[tid][2] = f2bf(qe.y);
    tailb[tid][3] = f2bf(qe.z);
    tailb[tid][4] = f2bf(tth.x + d.x);
    tailb[tid][5] = f2bf(tth.y + d.y);
    tailb[tid][6] = f2bf(tth.z + d.z);
    ibat_s[tid] = batch[rc];
  }
  __syncthreads();

  // ---- stage u rows (cols 7..134) + zero pad (cols 135..167) ----
  for (int idx = tid; idx < 64*128; idx += 512){
    const int e = idx >> 7, c = idx & 127;
    tailb[e][7 + c] = f2bf(u[(size_t)ibat_s[e]*128 + c]);
  }
  for (int idx = tid; idx < 64*33; idx += 512){
    const int e = idx / 33, c = idx % 33;
    tailb[e][135 + c] = 0;
  }

  const int lane = tid & 63, wv = tid >> 6;   // 8 waves; wave owns cols [16wv, 16wv+16)
  const int l15 = lane & 15, l4 = lane >> 4;
  const int col = wv*16 + l15;

  // ---- GEMM1 accumulators: 4 A-groups x 1 col-fragment ----
  f32x4 acc1[4];
  {
    const float bv = b1[col];
    #pragma unroll
    for (int a = 0; a < 4; ++a){
      #pragma unroll
      for (int r = 0; r < 4; ++r) acc1[a][r] = bv;
    }
  }

  const float* fps[3] = { xfi, xfj, ef };
  for (int fb = 0; fb < 3; ++fb){
    const float* F = fps[fb];
    __syncthreads();                         // previous slab consumed
    #pragma unroll
    for (int i = 0; i < 4; ++i){
      const int idx = i*512 + tid;
      const int e = idx >> 5, c4 = (idx & 31) << 2;
      long rr = base + e; if (rr >= E) rr = E-1;
      const float4 v = *reinterpret_cast<const float4*>(F + (size_t)rr*128 + c4);
      unsigned int* dst = reinterpret_cast<unsigned int*>(&fbuf[e][c4]);
      dst[0] = cvt2(v.x, v.y);
      dst[1] = cvt2(v.z, v.w);
    }
    __syncthreads();
    #pragma unroll
    for (int kc = 0; kc < 4; ++kc){
      const int kl = kc*32 + l4*8;
      bf16x8 afr[4];
      #pragma unroll
      for (int a = 0; a < 4; ++a)
        afr[a] = *reinterpret_cast<const bf16x8*>(&fbuf[a*16 + l15][kl]);
      bf16x8 Bv;
      if (WSP){
        Bv = *reinterpret_cast<const bf16x8*>(W1p + (size_t)col*544 + fb*128 + kl);
      } else {
        float w[8];
        #pragma unroll
        for (int j = 0; j < 8; ++j)
          w[j] = W1[(size_t)(fb*128 + kl + j)*128 + col];
        union { bf16x8 v; unsigned int ui[4]; } B;
        B.ui[0] = cvt2(w[0], w[1]);
        B.ui[1] = cvt2(w[2], w[3]);
        B.ui[2] = cvt2(w[4], w[5]);
        B.ui[3] = cvt2(w[6], w[7]);
        Bv = B.v;
      }
      #pragma unroll
      for (int a = 0; a < 4; ++a)
        acc1[a] = __builtin_amdgcn_mfma_f32_16x16x32_bf16(afr[a], Bv, acc1[a], 0, 0, 0);
    }
  }
  // tail k-chunks (k = 384..543) from tailb
  #pragma unroll
  for (int tc = 0; tc < 5; ++tc){
    const int kt = tc*32 + l4*8;
    bf16x8 afr[4];
    #pragma unroll
    for (int a = 0; a < 4; ++a)
      afr[a] = *reinterpret_cast<const bf16x8*>(&tailb[a*16 + l15][kt]);
    bf16x8 Bv;
    if (WSP){
      Bv = *reinterpret_cast<const bf16x8*>(W1p + (size_t)col*544 + 384 + kt);
    } else {
      float w[8];
      #pragma unroll
      for (int j = 0; j < 8; ++j){
        const int kk = 384 + kt + j;
        w[j] = (kk < 519) ? W1[(size_t)kk*128 + col] : 0.f;
      }
      union { bf16x8 v; unsigned int ui[4]; } B;
      B.ui[0] = cvt2(w[0], w[1]);
      B.ui[1] = cvt2(w[2], w[3]);
      B.ui[2] = cvt2(w[4], w[5]);
      B.ui[3] = cvt2(w[6], w[7]);
      Bv = B.v;
    }
    #pragma unroll
    for (int a = 0; a < 4; ++a)
      acc1[a] = __builtin_amdgcn_mfma_f32_16x16x32_bf16(afr[a], Bv, acc1[a], 0, 0, 0);
  }

  // ---- h = relu -> bf16 into dedicated hbf ----
  #pragma unroll
  for (int a = 0; a < 4; ++a){
    #pragma unroll
    for (int r = 0; r < 4; ++r)
      hbf[a*16 + l4*4 + r][col] = f2bf(fmaxf(acc1[a][r], 0.f));
  }
  __syncthreads();

  // ---- GEMM2: out = ef (fp32 global, late init) + b2 + h @ W2 ----
  f32x4 acc2[4];
  {
    const float bv2 = b2[col];
    #pragma unroll
    for (int a = 0; a < 4; ++a){
      #pragma unroll
      for (int r = 0; r < 4; ++r){
        long orow = base + a*16 + l4*4 + r;
        if (orow >= E) orow = E-1;
        acc2[a][r] = ef[(size_t)orow*128 + col] + bv2;
      }
    }
  }
  #pragma unroll
  for (int ks = 0; ks < 4; ++ks){
    const int k0 = ks*32 + l4*8;
    bf16x8 afr[4];
    #pragma unroll
    for (int a = 0; a < 4; ++a)
      afr[a] = *reinterpret_cast<const bf16x8*>(&hbf[a*16 + l15][k0]);
    bf16x8 Bv;
    if (WSP){
      Bv = *reinterpret_cast<const bf16x8*>(W2p + (size_t)col*128 + k0);
    } else {
      float w[8];
      #pragma unroll
      for (int j = 0; j < 8; ++j)
        w[j] = W2[(size_t)(k0 + j)*128 + col];
      union { bf16x8 v; unsigned int ui[4]; } B;
      B.ui[0] = cvt2(w[0], w[1]);
      B.ui[1] = cvt2(w[2], w[3]);
      B.ui[2] = cvt2(w[4], w[5]);
      B.ui[3] = cvt2(w[6], w[7]);
      Bv = B.v;
    }
    #pragma unroll
    for (int a = 0; a < 4; ++a)
      acc2[a] = __builtin_amdgcn_mfma_f32_16x16x32_bf16(afr[a], Bv, acc2[a], 0, 0, 0);
  }

  // ---- store edge_feat_out ----
  #pragma unroll
  for (int a = 0; a < 4; ++a){
    #pragma unroll
    for (int r = 0; r < 4; ++r){
      const long orow = base + a*16 + l4*4 + r;
      if (orow < E) outE[(size_t)orow*128 + col] = acc2[a][r];
    }
  }
}

extern "C" void kernel_launch(void* const* d_in, const int* in_sizes, int n_in,
                              void* d_out, int out_size, void* d_ws, size_t ws_size,
                              hipStream_t stream){
  const float* xfi  = (const float*)d_in[0];
  const float* xfj  = (const float*)d_in[1];
  const float* ef   = (const float*)d_in[2];
  const float* Ti   = (const float*)d_in[3];
  const float* Tj   = (const float*)d_in[4];
  const float* Th   = (const float*)d_in[5];
  const float* u    = (const float*)d_in[6];
  const int*   bat  = (const int*)d_in[7];
  const float* W1   = (const float*)d_in[8];
  const float* b1   = (const float*)d_in[9];
  const float* W2   = (const float*)d_in[10];
  const float* b2   = (const float*)d_in[11];
  const int E = in_sizes[0] / 128;

  float* outE = (float*)d_out;
  float* outT = outE + (size_t)E * 128;

  const int grid = (E + 63) / 64;
  const size_t need = (size_t)(128*544 + 128*128) * sizeof(unsigned short); // 172032 B
  if (d_ws != nullptr && ws_size >= need){
    unsigned short* W1p = (unsigned short*)d_ws;
    unsigned short* W2p = W1p + (size_t)128*544;
    prep_kernel<<<(128*544 + 128*128 + 255)/256, 256, 0, stream>>>(W1, W2, W1p, W2p);
    edge_k<true><<<grid, 512, 0, stream>>>(xfi, xfj, ef, Ti, Tj, Th, bat, u,
                                           W1, b1, W2, b2, W1p, W2p, outE, outT, E);
  } else {
    edge_k<false><<<grid, 512, 0, stream>>>(xfi, xfj, ef, Ti, Tj, Th, bat, u,
                                            W1, b1, W2, b2, nullptr, nullptr, outE, outT, E);
  }
}